// Round 11
// baseline (168.410 us; speedup 1.0000x reference)
//
#include <hip/hip_runtime.h>
#include <hip/hip_fp16.h>

#define NN 50000
#define NE 800000
#define HID 128
#define NSL 128                      // edge slices
#define NRG 4                        // node ranges of 16384
#define HB  (NRG * NSL)              // 512 histogram blocks
#define EPS (NE / NSL)               // 6250 edges per slice
#define GEMMB ((NN + 63) / 64)       // 64 rows per block

typedef _Float16 f16x8 __attribute__((ext_vector_type(8)));
typedef float f32x4 __attribute__((ext_vector_type(4)));

static __device__ __forceinline__ float lrelu(float x) { return x > 0.f ? x : 0.01f * x; }

// ---------------- W converter: fp32 [128][128] -> transposed + pre-swizzled fp16 ----------------
__global__ void convW2(const float* __restrict__ W1, const float* __restrict__ W2,
                       _Float16* __restrict__ W1o, _Float16* __restrict__ W2o) {
    int i = blockIdx.x * 256 + threadIdx.x;           // 0..32767
    const float* W = (i < 16384) ? W1 : W2;
    _Float16* O = (i < 16384) ? W1o : W2o;
    int j = i & 16383;
    int p = j * 2;
    int q = p ^ (((p >> 8) & 7) << 4);
    int c = q >> 8;               // output column (0..127)
    int k = (q & 255) >> 1;       // k index (0..127)
    O[j] = (_Float16)W[k * 128 + c];
}

// ---------------- MFMA GEMM body (LDS slab passed in; 32 KB used) ----------------
template <bool AF16, bool SCALE>
static __device__ __forceinline__ void gemm_body(const void* __restrict__ A,
                                                 const _Float16* __restrict__ Wsw,
                                                 const float* __restrict__ nout,
                                                 _Float16* __restrict__ Y, int r0, int n,
                                                 _Float16* Wt) {
    int t = threadIdx.x;
    #pragma unroll
    for (int i = 0; i < 8; i++) {
        int idx = t + i * 256;
        *(((float4*)Wt) + idx) = ((const float4*)Wsw)[idx];
    }
    int wid = t >> 6, lane = t & 63;
    int kgrp = lane >> 4, l15 = lane & 15;

    int r = r0 + wid * 16 + l15;
    f16x8 a[4];
    #pragma unroll
    for (int ks = 0; ks < 4; ks++)
        #pragma unroll
        for (int j = 0; j < 8; j++) a[ks][j] = (_Float16)0.f;
    if (r < n) {
        if (AF16) {
            const _Float16* Ah = (const _Float16*)A + (size_t)r * HID + kgrp * 8;
            #pragma unroll
            for (int ks = 0; ks < 4; ks++) a[ks] = *(const f16x8*)(Ah + ks * 32);
        } else {
            const float* Af = (const float*)A + (size_t)r * HID + kgrp * 8;
            #pragma unroll
            for (int ks = 0; ks < 4; ks++) {
                float4 lo = *(const float4*)(Af + ks * 32);
                float4 hi = *(const float4*)(Af + ks * 32 + 4);
                a[ks][0] = (_Float16)lo.x; a[ks][1] = (_Float16)lo.y;
                a[ks][2] = (_Float16)lo.z; a[ks][3] = (_Float16)lo.w;
                a[ks][4] = (_Float16)hi.x; a[ks][5] = (_Float16)hi.y;
                a[ks][6] = (_Float16)hi.z; a[ks][7] = (_Float16)hi.w;
            }
        }
    }
    __syncthreads();

    f32x4 acc[8];
    #pragma unroll
    for (int td = 0; td < 8; td++)
        #pragma unroll
        for (int j = 0; j < 4; j++) acc[td][j] = 0.f;

    const char* base = (const char*)Wt;
    #pragma unroll
    for (int ks = 0; ks < 4; ks++) {
        #pragma unroll
        for (int td = 0; td < 8; td++) {
            int c = td * 16 + l15;
            int addr = ((c << 8) + 64 * ks + 16 * kgrp) ^ ((c & 7) << 4);
            f16x8 b = *(const f16x8*)(base + addr);
            acc[td] = __builtin_amdgcn_mfma_f32_16x16x32_f16(a[ks], b, acc[td], 0, 0, 0);
        }
    }

    int ro = r0 + wid * 16 + kgrp * 4;   // C/D: col = lane&15, row = (lane>>4)*4 + reg
    float no[4] = {1.f, 1.f, 1.f, 1.f};
    if (SCALE) {
        #pragma unroll
        for (int reg = 0; reg < 4; reg++) {
            int orow = ro + reg;
            if (orow < n) no[reg] = nout[orow];
        }
    }
    #pragma unroll
    for (int td = 0; td < 8; td++) {
        #pragma unroll
        for (int reg = 0; reg < 4; reg++) {
            int orow = ro + reg;
            if (orow < n) Y[(size_t)orow * HID + td * 16 + l15] = (_Float16)(acc[td][reg] * no[reg]);
        }
    }
}

// ------- mega_h1: LDS-privatized degree histograms + local rank (blocks < HB) || MFMA GEMM-1 -------
// Node n -> range r=n>>14, packed word (n&16383)>>1, half n&1 (16-bit counters, per-slice deg <= 6250).
__global__ __launch_bounds__(256) void mega_h1(const float* __restrict__ feat,
                                               const _Float16* __restrict__ W1sw,
                                               _Float16* __restrict__ Yh,
                                               const int* __restrict__ src, const int* __restrict__ dst,
                                               unsigned short* __restrict__ rank_local,
                                               int* __restrict__ H_in, int* __restrict__ H_out, int n) {
    __shared__ __align__(16) int lds[16384];   // 64 KB slab (hist: hin|hout; gemm: 32 KB W tile)
    int b = blockIdx.x, t = threadIdx.x;
    if (b < HB) {
        int r = b >> 7, s = b & (NSL - 1);
        #pragma unroll
        for (int i = 0; i < 16; i++) ((int4*)lds)[t + i * 256] = make_int4(0, 0, 0, 0);
        __syncthreads();
        int* hin  = lds;          // 8192 ints: packed deg_in counters for range r
        int* hout = lds + 8192;   // 8192 ints: packed deg_out counters
        int e0 = s * EPS;
        for (int i = t; i < EPS; i += 256) {
            int e = e0 + i;
            int sd = src[e];
            int dd = dst[e];
            if ((sd >> 14) == r) atomicAdd(&hout[(sd & 16383) >> 1], 1 << ((sd & 1) << 4));
            if ((dd >> 14) == r) {
                int old = atomicAdd(&hin[(dd & 16383) >> 1], 1 << ((dd & 1) << 4));
                rank_local[e] = (unsigned short)((old >> ((dd & 1) << 4)) & 0xffff);
            }
        }
        __syncthreads();
        int4* gHin  = (int4*)(H_in  + (size_t)b * 8192);
        int4* gHout = (int4*)(H_out + (size_t)b * 8192);
        #pragma unroll
        for (int i = 0; i < 8; i++) {
            gHin[t + i * 256]  = ((int4*)hin)[t + i * 256];
            gHout[t + i * 256] = ((int4*)hout)[t + i * 256];
        }
        return;
    }
    gemm_body<false, false>(feat, W1sw, nullptr, Yh, (b - HB) * 64, n, (_Float16*)lds);
}

// ---- prefix over slices: H_in -> in-place exclusive prefix P (packed); emit deg_in/deg_out ----
__global__ void prefix_k(int* __restrict__ H_in, const int* __restrict__ H_out,
                         int* __restrict__ deg_in, int* __restrict__ deg_out) {
    int tid = blockIdx.x * 256 + threadIdx.x;   // 0..32767
    int r = tid >> 13, w = tid & 8191;
    size_t base = (size_t)r << 20;              // r * NSL * 8192
    int runIn = 0, runOut = 0;
    for (int s = 0; s < NSL; s++) {
        size_t idx = base + ((size_t)s << 13) + w;
        int hv = H_in[idx];
        H_in[idx] = runIn;                      // packed exclusive prefix (no cross-half carry)
        runIn += hv;
        runOut += H_out[idx];
    }
    int n0 = (r << 14) | (w << 1), n1 = n0 | 1;
    if (n0 < NN) { deg_in[n0] = runIn & 0xffff;               deg_out[n0] = runOut & 0xffff; }
    if (n1 < NN) { deg_in[n1] = (int)((unsigned)runIn >> 16); deg_out[n1] = (int)((unsigned)runOut >> 16); }
}

// ---------------- prefix scan trio (scan1 fused with norm computation) ----------------
__global__ void scan1(const int* __restrict__ deg_in, const int* __restrict__ deg_out,
                      int* __restrict__ excl, int* __restrict__ bsums,
                      float* __restrict__ norm_out, float* __restrict__ norm_in, int n) {
    __shared__ int ws[16];
    int t = threadIdx.x;
    int i = blockIdx.x * 1024 + t;
    int v = (i < n) ? deg_in[i] : 0;
    if (i < n) {
        norm_in[i]  = rsqrtf((float)max(v, 1));
        norm_out[i] = rsqrtf((float)max(deg_out[i], 1));
    }
    int x = v;
    #pragma unroll
    for (int o = 1; o < 64; o <<= 1) {
        int y = __shfl_up(x, o, 64);
        if ((t & 63) >= o) x += y;
    }
    if ((t & 63) == 63) ws[t >> 6] = x;
    __syncthreads();
    if (t < 16) {
        int s = ws[t];
        #pragma unroll
        for (int o = 1; o < 16; o <<= 1) {
            int y = __shfl_up(s, o, 16);
            if (t >= o) s += y;
        }
        ws[t] = s;
    }
    __syncthreads();
    int wid = t >> 6;
    int pre = wid ? ws[wid - 1] : 0;
    if (i < n) excl[i] = pre + x - v;
    if (t == 1023) bsums[blockIdx.x] = ws[15];
}

__global__ void scan2(const int* __restrict__ bsums, int* __restrict__ boff, int nb,
                      int* __restrict__ total_out) {
    int t = threadIdx.x;
    int v = (t < nb) ? bsums[t] : 0;
    int x = v;
    #pragma unroll
    for (int o = 1; o < 64; o <<= 1) {
        int y = __shfl_up(x, o, 64);
        if (t >= o) x += y;
    }
    if (t < nb) boff[t] = x - v;
    if (t == 63) total_out[0] = x;
}

__global__ void scan3(int* __restrict__ off, const int* __restrict__ boff, int n) {
    int i = blockIdx.x * 1024 + threadIdx.x;
    if (i < n) off[i] += boff[blockIdx.x];
}

// ---------------- CSR fill: atomic-free (local rank + slice-prefix) ----------------
__global__ void fill_kernel(const int* __restrict__ src, const int* __restrict__ dst,
                            const int* __restrict__ off, const unsigned short* __restrict__ rank_local,
                            const int* __restrict__ P, int* __restrict__ eidx, int E) {
    int e = blockIdx.x * blockDim.x + threadIdx.x;
    if (e < E) {
        int dd = dst[e];
        int s = e / EPS;
        size_t idx = ((size_t)(((dd >> 14) << 7) + s) << 13) + ((dd & 16383) >> 1);
        int pv = (P[idx] >> ((dd & 1) << 4)) & 0xffff;
        eidx[off[dd] + (int)rank_local[e] + pv] = src[e];
    }
}

// ---- fused aggregate (depth-4 fp16 gather, packed-fp16 partial sums) + nin + bias + LN + LeakyReLU ----
template <bool PROJ, bool NOUTG>
__global__ __launch_bounds__(256) void agg_post(const __half* __restrict__ Yh, const int* __restrict__ off,
                                                const int* __restrict__ eidx, const float* __restrict__ nout,
                                                const float* __restrict__ nin,
                                                const float* __restrict__ bias, const float* __restrict__ gam,
                                                const float* __restrict__ bet, __half* __restrict__ Xo,
                                                const float* __restrict__ W3, float* __restrict__ Z, int n) {
    int w = threadIdx.x >> 6, lane = threadIdx.x & 63;
    int r = blockIdx.x * 4 + w;
    if (r >= n) return;
    int grp = lane >> 4;
    int f0 = (lane & 15) * 8;
    int s = off[r], e = off[r + 1];

    float af[8];
    #pragma unroll
    for (int i = 0; i < 8; i++) af[i] = 0.f;

    union U { float4 f; __half2 h[4]; };
    const __half2 hz = __float2half2_rn(0.f);
    for (int j = s; j < e; j += 16) {
        int i0 = j + grp, i1 = i0 + 4, i2 = i0 + 8, i3 = i0 + 12;
        int s0 = (i0 < e) ? eidx[i0] : -1;
        int s1 = (i1 < e) ? eidx[i1] : -1;
        int s2 = (i2 < e) ? eidx[i2] : -1;
        int s3 = (i3 < e) ? eidx[i3] : -1;
        U u0, u1, u2, u3;
        float n0 = 1.f, n1 = 1.f, n2 = 1.f, n3 = 1.f;
        if (s0 >= 0) u0.f = *(const float4*)&Yh[(size_t)s0 * HID + f0];
        if (s1 >= 0) u1.f = *(const float4*)&Yh[(size_t)s1 * HID + f0];
        if (s2 >= 0) u2.f = *(const float4*)&Yh[(size_t)s2 * HID + f0];
        if (s3 >= 0) u3.f = *(const float4*)&Yh[(size_t)s3 * HID + f0];
        if (NOUTG) {
            if (s0 >= 0) n0 = nout[s0];
            if (s1 >= 0) n1 = nout[s1];
            if (s2 >= 0) n2 = nout[s2];
            if (s3 >= 0) n3 = nout[s3];
        }
        // packed-fp16 partial sum over the (<=4) edges of this iteration
        __half2 ph[4] = {hz, hz, hz, hz};
        if (NOUTG) {
            if (s0 >= 0) { __half2 nh = __float2half2_rn(n0);
                #pragma unroll
                for (int k = 0; k < 4; k++) ph[k] = __hfma2(nh, u0.h[k], ph[k]); }
            if (s1 >= 0) { __half2 nh = __float2half2_rn(n1);
                #pragma unroll
                for (int k = 0; k < 4; k++) ph[k] = __hfma2(nh, u1.h[k], ph[k]); }
            if (s2 >= 0) { __half2 nh = __float2half2_rn(n2);
                #pragma unroll
                for (int k = 0; k < 4; k++) ph[k] = __hfma2(nh, u2.h[k], ph[k]); }
            if (s3 >= 0) { __half2 nh = __float2half2_rn(n3);
                #pragma unroll
                for (int k = 0; k < 4; k++) ph[k] = __hfma2(nh, u3.h[k], ph[k]); }
        } else {
            if (s0 >= 0) {
                #pragma unroll
                for (int k = 0; k < 4; k++) ph[k] = __hadd2(ph[k], u0.h[k]); }
            if (s1 >= 0) {
                #pragma unroll
                for (int k = 0; k < 4; k++) ph[k] = __hadd2(ph[k], u1.h[k]); }
            if (s2 >= 0) {
                #pragma unroll
                for (int k = 0; k < 4; k++) ph[k] = __hadd2(ph[k], u2.h[k]); }
            if (s3 >= 0) {
                #pragma unroll
                for (int k = 0; k < 4; k++) ph[k] = __hadd2(ph[k], u3.h[k]); }
        }
        // fold into fp32 accumulators once per iteration
        #pragma unroll
        for (int k = 0; k < 4; k++) {
            float2 t2 = __half22float2(ph[k]);
            af[2 * k] += t2.x;
            af[2 * k + 1] += t2.y;
        }
    }
    #pragma unroll
    for (int i = 0; i < 8; i++) {
        af[i] += __shfl_xor(af[i], 16, 64);
        af[i] += __shfl_xor(af[i], 32, 64);
    }

    float ni = nin[r];
    float4 b0 = *(const float4*)&bias[f0];
    float4 b1 = *(const float4*)&bias[f0 + 4];
    float v[8];
    v[0] = af[0] * ni + b0.x; v[1] = af[1] * ni + b0.y;
    v[2] = af[2] * ni + b0.z; v[3] = af[3] * ni + b0.w;
    v[4] = af[4] * ni + b1.x; v[5] = af[5] * ni + b1.y;
    v[6] = af[6] * ni + b1.z; v[7] = af[7] * ni + b1.w;

    float sum = 0.f;
    #pragma unroll
    for (int i = 0; i < 8; i++) sum += v[i];
    #pragma unroll
    for (int o = 8; o >= 1; o >>= 1) sum += __shfl_xor(sum, o, 64);
    float mu = sum * (1.f / 128.f);

    float d[8], vs = 0.f;
    #pragma unroll
    for (int i = 0; i < 8; i++) { d[i] = v[i] - mu; vs += d[i] * d[i]; }
    #pragma unroll
    for (int o = 8; o >= 1; o >>= 1) vs += __shfl_xor(vs, o, 64);
    float rs = rsqrtf(vs * (1.f / 128.f) + 1e-5f);

    float4 g0 = *(const float4*)&gam[f0];
    float4 g1 = *(const float4*)&gam[f0 + 4];
    float4 e0 = *(const float4*)&bet[f0];
    float4 e1 = *(const float4*)&bet[f0 + 4];
    float x[8];
    x[0] = lrelu(d[0] * rs * g0.x + e0.x);
    x[1] = lrelu(d[1] * rs * g0.y + e0.y);
    x[2] = lrelu(d[2] * rs * g0.z + e0.z);
    x[3] = lrelu(d[3] * rs * g0.w + e0.w);
    x[4] = lrelu(d[4] * rs * g1.x + e1.x);
    x[5] = lrelu(d[5] * rs * g1.y + e1.y);
    x[6] = lrelu(d[6] * rs * g1.z + e1.z);
    x[7] = lrelu(d[7] * rs * g1.w + e1.w);

    if (PROJ) {
        float z0 = 0.f, z1 = 0.f;
        #pragma unroll
        for (int i = 0; i < 8; i++) {
            float2 w3 = *(const float2*)&W3[(f0 + i) * 2];
            z0 = fmaf(x[i], w3.x, z0);
            z1 = fmaf(x[i], w3.y, z1);
        }
        #pragma unroll
        for (int o = 8; o >= 1; o >>= 1) {
            z0 += __shfl_xor(z0, o, 64);
            z1 += __shfl_xor(z1, o, 64);
        }
        if (lane == 0) {
            float no = nout[r];
            *(float2*)&Z[r * 2] = make_float2(z0 * no, z1 * no);
        }
    } else {
        if (grp == 0) {
            union { __half2 h[4]; float4 f; } o;
            o.h[0] = __floats2half2_rn(x[0], x[1]);
            o.h[1] = __floats2half2_rn(x[2], x[3]);
            o.h[2] = __floats2half2_rn(x[4], x[5]);
            o.h[3] = __floats2half2_rn(x[6], x[7]);
            *(float4*)&Xo[(size_t)r * HID + f0] = o.f;
        }
    }
}

// ---------------- GEMM layer 2 (fp16 A, output scaled by norm_out row) ----------------
__global__ __launch_bounds__(256) void gemm2(const _Float16* __restrict__ Xh,
                                             const _Float16* __restrict__ W2sw,
                                             const float* __restrict__ nout,
                                             _Float16* __restrict__ Yh, int n) {
    __shared__ __align__(16) _Float16 Wt[16384];  // 32 KB
    gemm_body<true, true>(Xh, W2sw, nout, Yh, blockIdx.x * 64, n, Wt);
}

// ---------------- final aggregation (2 dims), 4-way unrolled ----------------
__global__ void agg3(const float* __restrict__ Z, const int* __restrict__ off,
                     const int* __restrict__ eidx, const float* __restrict__ nin,
                     const float* __restrict__ b3, float* __restrict__ out, int n) {
    int r = blockIdx.x * blockDim.x + threadIdx.x;
    if (r < n) {
        int s = off[r], e = off[r + 1];
        float p0 = 0.f, p1 = 0.f, q0 = 0.f, q1 = 0.f;
        float u0 = 0.f, u1 = 0.f, w0 = 0.f, w1 = 0.f;
        int j = s;
        for (; j + 3 < e; j += 4) {
            float2 v0 = *(const float2*)&Z[eidx[j] * 2];
            float2 v1 = *(const float2*)&Z[eidx[j + 1] * 2];
            float2 v2 = *(const float2*)&Z[eidx[j + 2] * 2];
            float2 v3 = *(const float2*)&Z[eidx[j + 3] * 2];
            p0 += v0.x; p1 += v0.y;
            q0 += v1.x; q1 += v1.y;
            u0 += v2.x; u1 += v2.y;
            w0 += v3.x; w1 += v3.y;
        }
        for (; j < e; ++j) {
            float2 v = *(const float2*)&Z[eidx[j] * 2];
            p0 += v.x; p1 += v.y;
        }
        float a0 = (p0 + q0) + (u0 + w0);
        float a1 = (p1 + q1) + (u1 + w1);
        float ni = nin[r];
        out[r * 2 + 0] = a0 * ni + b3[0];
        out[r * 2 + 1] = a1 * ni + b3[1];
    }
}

extern "C" void kernel_launch(void* const* d_in, const int* in_sizes, int n_in,
                              void* d_out, int out_size, void* d_ws, size_t ws_size,
                              hipStream_t stream) {
    const float* feat = (const float*)d_in[0];
    const int* src = (const int*)d_in[1];
    const int* dst = (const int*)d_in[2];
    const float* W1 = (const float*)d_in[3];
    const float* b1 = (const float*)d_in[4];
    const float* W2 = (const float*)d_in[5];
    const float* b2 = (const float*)d_in[6];
    const float* W3 = (const float*)d_in[7];
    const float* b3 = (const float*)d_in[8];
    const float* g1 = (const float*)d_in[9];
    const float* be1 = (const float*)d_in[10];
    const float* g2 = (const float*)d_in[11];
    const float* be2 = (const float*)d_in[12];
    float* out = (float*)d_out;

    char* p = (char*)d_ws;
    auto carve = [&](size_t bytes) -> char* {
        char* q = p;
        p += (bytes + 255) & ~(size_t)255;
        return q;
    };
    int* deg_out = (int*)carve(NN * 4);
    int* deg_in  = (int*)carve(NN * 4);
    float* norm_out = (float*)carve(NN * 4);
    float* norm_in  = (float*)carve(NN * 4);
    int* off     = (int*)carve((NN + 1) * 4);
    int* bsums   = (int*)carve(64 * 4);
    int* boff    = (int*)carve(64 * 4);
    int* eidx    = (int*)carve((size_t)NE * 4);
    unsigned short* rank_local = (unsigned short*)carve((size_t)NE * 2);
    int* H_in  = (int*)carve((size_t)HB * 8192 * 4);   // 16 MB (becomes P in-place; Xh aliases after fill)
    int* H_out = (int*)carve((size_t)HB * 8192 * 4);   // 16 MB (dead after prefix_k; Z aliases)
    _Float16* W1sw = (_Float16*)carve(16384 * 2);
    _Float16* W2sw = (_Float16*)carve(16384 * 2);
    _Float16* Yh = (_Float16*)carve((size_t)NN * HID * 2);
    // aliases into dead H buffers (stream-ordered: H_in dead after fill_kernel, H_out after prefix_k)
    __half* Xh = (__half*)H_in;                        // 12.8 MB <= 16 MB
    float* Z = (float*)H_out;                          // 0.4 MB

    convW2<<<128, 256, 0, stream>>>(W1, W2, W1sw, W2sw);

    // LDS-privatized degree histograms + local ranks || MFMA GEMM-1 (no global atomics)
    mega_h1<<<HB + GEMMB, 256, 0, stream>>>(feat, W1sw, Yh, src, dst, rank_local, H_in, H_out, NN);

    // exclusive prefix over slices (P in-place in H_in) + final degrees
    prefix_k<<<128, 256, 0, stream>>>(H_in, H_out, deg_in, deg_out);

    // scan trio (scan1 fused with norms)
    int nb = (NN + 1023) / 1024;  // 49
    scan1<<<nb, 1024, 0, stream>>>(deg_in, deg_out, off, bsums, norm_out, norm_in, NN);
    scan2<<<1, 64, 0, stream>>>(bsums, boff, nb, off + NN);
    scan3<<<nb, 1024, 0, stream>>>(off, boff, NN);

    // CSR fill (atomic-free)
    fill_kernel<<<(NE + 255) / 256, 256, 0, stream>>>(src, dst, off, rank_local, H_in, eidx, NE);

    // layer 1 aggregation (folds nout[src]) -> fp16 X (aliased onto H_in)
    agg_post<false, true><<<(NN + 3) / 4, 256, 0, stream>>>((const __half*)Yh, off, eidx, norm_out, norm_in,
                                                            b1, g1, be1, Xh, nullptr, nullptr, NN);
    // layer 2 GEMM (fp16 MFMA, output pre-scaled by norm_out)
    gemm2<<<GEMMB, 256, 0, stream>>>((const _Float16*)Xh, W2sw, norm_out, Yh, NN);
    // layer 2 aggregation (Yh pre-scaled) fused with layer-3 projection -> Z (aliased onto H_out)
    agg_post<true, false><<<(NN + 3) / 4, 256, 0, stream>>>((const __half*)Yh, off, eidx, norm_out, norm_in,
                                                            b2, g2, be2, nullptr, W3, Z, NN);
    // layer 3 aggregation -> out
    agg3<<<(NN + 255) / 256, 256, 0, stream>>>(Z, off, eidx, norm_in, b3, out, NN);
}

// Round 12
// 164.886 us; speedup vs baseline: 1.0214x; 1.0214x over previous
//
#include <hip/hip_runtime.h>
#include <hip/hip_fp16.h>

#define NN 50000
#define NE 800000
#define HID 128
#define NSL 128                      // edge slices
#define NRG 8                        // node ranges of 8192
#define HB  (NRG * NSL)              // 1024 histogram blocks
#define EPS (NE / NSL)               // 6250 edges per slice
#define GEMMB ((NN + 63) / 64)       // 64 rows per block

typedef _Float16 f16x8 __attribute__((ext_vector_type(8)));
typedef float f32x4 __attribute__((ext_vector_type(4)));

static __device__ __forceinline__ float lrelu(float x) { return x > 0.f ? x : 0.01f * x; }

// ---------------- W converter: fp32 [128][128] -> transposed + pre-swizzled fp16 ----------------
__global__ void convW2(const float* __restrict__ W1, const float* __restrict__ W2,
                       _Float16* __restrict__ W1o, _Float16* __restrict__ W2o) {
    int i = blockIdx.x * 256 + threadIdx.x;           // 0..32767
    const float* W = (i < 16384) ? W1 : W2;
    _Float16* O = (i < 16384) ? W1o : W2o;
    int j = i & 16383;
    int p = j * 2;
    int q = p ^ (((p >> 8) & 7) << 4);
    int c = q >> 8;               // output column (0..127)
    int k = (q & 255) >> 1;       // k index (0..127)
    O[j] = (_Float16)W[k * 128 + c];
}

// ---------------- MFMA GEMM body (32 KB LDS slab passed in) ----------------
template <bool AF16, bool SCALE>
static __device__ __forceinline__ void gemm_body(const void* __restrict__ A,
                                                 const _Float16* __restrict__ Wsw,
                                                 const float* __restrict__ nout,
                                                 _Float16* __restrict__ Y, int r0, int n,
                                                 _Float16* Wt) {
    int t = threadIdx.x;
    #pragma unroll
    for (int i = 0; i < 8; i++) {
        int idx = t + i * 256;
        *(((float4*)Wt) + idx) = ((const float4*)Wsw)[idx];
    }
    int wid = t >> 6, lane = t & 63;
    int kgrp = lane >> 4, l15 = lane & 15;

    int r = r0 + wid * 16 + l15;
    f16x8 a[4];
    #pragma unroll
    for (int ks = 0; ks < 4; ks++)
        #pragma unroll
        for (int j = 0; j < 8; j++) a[ks][j] = (_Float16)0.f;
    if (r < n) {
        if (AF16) {
            const _Float16* Ah = (const _Float16*)A + (size_t)r * HID + kgrp * 8;
            #pragma unroll
            for (int ks = 0; ks < 4; ks++) a[ks] = *(const f16x8*)(Ah + ks * 32);
        } else {
            const float* Af = (const float*)A + (size_t)r * HID + kgrp * 8;
            #pragma unroll
            for (int ks = 0; ks < 4; ks++) {
                float4 lo = *(const float4*)(Af + ks * 32);
                float4 hi = *(const float4*)(Af + ks * 32 + 4);
                a[ks][0] = (_Float16)lo.x; a[ks][1] = (_Float16)lo.y;
                a[ks][2] = (_Float16)lo.z; a[ks][3] = (_Float16)lo.w;
                a[ks][4] = (_Float16)hi.x; a[ks][5] = (_Float16)hi.y;
                a[ks][6] = (_Float16)hi.z; a[ks][7] = (_Float16)hi.w;
            }
        }
    }
    __syncthreads();

    f32x4 acc[8];
    #pragma unroll
    for (int td = 0; td < 8; td++)
        #pragma unroll
        for (int j = 0; j < 4; j++) acc[td][j] = 0.f;

    const char* base = (const char*)Wt;
    #pragma unroll
    for (int ks = 0; ks < 4; ks++) {
        #pragma unroll
        for (int td = 0; td < 8; td++) {
            int c = td * 16 + l15;
            int addr = ((c << 8) + 64 * ks + 16 * kgrp) ^ ((c & 7) << 4);
            f16x8 b = *(const f16x8*)(base + addr);
            acc[td] = __builtin_amdgcn_mfma_f32_16x16x32_f16(a[ks], b, acc[td], 0, 0, 0);
        }
    }

    int ro = r0 + wid * 16 + kgrp * 4;   // C/D: col = lane&15, row = (lane>>4)*4 + reg
    float no[4] = {1.f, 1.f, 1.f, 1.f};
    if (SCALE) {
        #pragma unroll
        for (int reg = 0; reg < 4; reg++) {
            int orow = ro + reg;
            if (orow < n) no[reg] = nout[orow];
        }
    }
    #pragma unroll
    for (int td = 0; td < 8; td++) {
        #pragma unroll
        for (int reg = 0; reg < 4; reg++) {
            int orow = ro + reg;
            if (orow < n) Y[(size_t)orow * HID + td * 16 + l15] = (_Float16)(acc[td][reg] * no[reg]);
        }
    }
}

// ------- mega_h1: 32KB LDS degree histograms + local rank (blocks < HB) || MFMA GEMM-1 -------
// Node n -> range r=n>>13, packed word (n&8191)>>1, half n&1 (16-bit counters, per-slice deg <= 6250).
__global__ __launch_bounds__(256) void mega_h1(const float* __restrict__ feat,
                                               const _Float16* __restrict__ W1sw,
                                               _Float16* __restrict__ Yh,
                                               const int* __restrict__ src, const int* __restrict__ dst,
                                               unsigned short* __restrict__ rank_local,
                                               int* __restrict__ H_in, int* __restrict__ H_out, int n) {
    __shared__ __align__(16) int lds[8192];    // 32 KB slab (hist: hin|hout; gemm: W tile)
    int b = blockIdx.x, t = threadIdx.x;
    if (b < HB) {
        int r = b >> 7, s = b & (NSL - 1);
        #pragma unroll
        for (int i = 0; i < 8; i++) ((int4*)lds)[t + i * 256] = make_int4(0, 0, 0, 0);
        __syncthreads();
        int* hin  = lds;          // 4096 ints: packed deg_in counters for range r
        int* hout = lds + 4096;   // 4096 ints: packed deg_out counters
        int e0 = s * EPS;
        for (int i = t; i < EPS; i += 256) {
            int e = e0 + i;
            int sd = src[e];
            int dd = dst[e];
            if ((sd >> 13) == r) atomicAdd(&hout[(sd & 8191) >> 1], 1 << ((sd & 1) << 4));
            if ((dd >> 13) == r) {
                int old = atomicAdd(&hin[(dd & 8191) >> 1], 1 << ((dd & 1) << 4));
                rank_local[e] = (unsigned short)((old >> ((dd & 1) << 4)) & 0xffff);
            }
        }
        __syncthreads();
        int4* gHin  = (int4*)(H_in  + (size_t)b * 4096);
        int4* gHout = (int4*)(H_out + (size_t)b * 4096);
        #pragma unroll
        for (int i = 0; i < 4; i++) {
            gHin[t + i * 256]  = ((int4*)hin)[t + i * 256];
            gHout[t + i * 256] = ((int4*)hout)[t + i * 256];
        }
        return;
    }
    gemm_body<false, false>(feat, W1sw, nullptr, Yh, (b - HB) * 64, n, (_Float16*)lds);
}

// ---- prefix over slices: H_in -> in-place exclusive prefix P (packed); emit deg_in/deg_out ----
__global__ void prefix_k(int* __restrict__ H_in, const int* __restrict__ H_out,
                         int* __restrict__ deg_in, int* __restrict__ deg_out) {
    int tid = blockIdx.x * 256 + threadIdx.x;   // 0..32767
    int r = tid >> 12, w = tid & 4095;
    size_t base = (size_t)r << 19;              // r * NSL * 4096
    int runIn = 0, runOut = 0;
    for (int s = 0; s < NSL; s++) {
        size_t idx = base + ((size_t)s << 12) + w;
        int hv = H_in[idx];
        H_in[idx] = runIn;                      // packed exclusive prefix (no cross-half carry)
        runIn += hv;
        runOut += H_out[idx];
    }
    int n0 = (r << 13) | (w << 1), n1 = n0 | 1;
    if (n0 < NN) { deg_in[n0] = runIn & 0xffff;               deg_out[n0] = runOut & 0xffff; }
    if (n1 < NN) { deg_in[n1] = (int)((unsigned)runIn >> 16); deg_out[n1] = (int)((unsigned)runOut >> 16); }
}

// ---------------- prefix scan trio (scan1 fused with norm computation) ----------------
__global__ void scan1(const int* __restrict__ deg_in, const int* __restrict__ deg_out,
                      int* __restrict__ excl, int* __restrict__ bsums,
                      float* __restrict__ norm_out, float* __restrict__ norm_in, int n) {
    __shared__ int ws[16];
    int t = threadIdx.x;
    int i = blockIdx.x * 1024 + t;
    int v = (i < n) ? deg_in[i] : 0;
    if (i < n) {
        norm_in[i]  = rsqrtf((float)max(v, 1));
        norm_out[i] = rsqrtf((float)max(deg_out[i], 1));
    }
    int x = v;
    #pragma unroll
    for (int o = 1; o < 64; o <<= 1) {
        int y = __shfl_up(x, o, 64);
        if ((t & 63) >= o) x += y;
    }
    if ((t & 63) == 63) ws[t >> 6] = x;
    __syncthreads();
    if (t < 16) {
        int s = ws[t];
        #pragma unroll
        for (int o = 1; o < 16; o <<= 1) {
            int y = __shfl_up(s, o, 16);
            if (t >= o) s += y;
        }
        ws[t] = s;
    }
    __syncthreads();
    int wid = t >> 6;
    int pre = wid ? ws[wid - 1] : 0;
    if (i < n) excl[i] = pre + x - v;
    if (t == 1023) bsums[blockIdx.x] = ws[15];
}

__global__ void scan2(const int* __restrict__ bsums, int* __restrict__ boff, int nb,
                      int* __restrict__ total_out) {
    int t = threadIdx.x;
    int v = (t < nb) ? bsums[t] : 0;
    int x = v;
    #pragma unroll
    for (int o = 1; o < 64; o <<= 1) {
        int y = __shfl_up(x, o, 64);
        if (t >= o) x += y;
    }
    if (t < nb) boff[t] = x - v;
    if (t == 63) total_out[0] = x;
}

__global__ void scan3(int* __restrict__ off, const int* __restrict__ boff, int n) {
    int i = blockIdx.x * 1024 + threadIdx.x;
    if (i < n) off[i] += boff[blockIdx.x];
}

// ---------------- CSR fill: atomic-free (local rank + slice-prefix) ----------------
__global__ void fill_kernel(const int* __restrict__ src, const int* __restrict__ dst,
                            const int* __restrict__ off, const unsigned short* __restrict__ rank_local,
                            const int* __restrict__ P, int* __restrict__ eidx, int E) {
    int e = blockIdx.x * blockDim.x + threadIdx.x;
    if (e < E) {
        int dd = dst[e];
        int s = e / EPS;
        size_t idx = ((size_t)(((dd >> 13) << 7) + s) << 12) + ((dd & 8191) >> 1);
        int pv = (P[idx] >> ((dd & 1) << 4)) & 0xffff;
        eidx[off[dd] + (int)rank_local[e] + pv] = src[e];
    }
}

// ---- fused aggregate (depth-4 fp16 gather) + nin + bias + LN + LeakyReLU ----
template <bool PROJ, bool NOUTG>
__global__ __launch_bounds__(256) void agg_post(const __half* __restrict__ Yh, const int* __restrict__ off,
                                                const int* __restrict__ eidx, const float* __restrict__ nout,
                                                const float* __restrict__ nin,
                                                const float* __restrict__ bias, const float* __restrict__ gam,
                                                const float* __restrict__ bet, __half* __restrict__ Xo,
                                                const float* __restrict__ W3, float* __restrict__ Z, int n) {
    int w = threadIdx.x >> 6, lane = threadIdx.x & 63;
    int r = blockIdx.x * 4 + w;
    if (r >= n) return;
    int grp = lane >> 4;
    int f0 = (lane & 15) * 8;
    int s = off[r], e = off[r + 1];

    float af[8];
    #pragma unroll
    for (int i = 0; i < 8; i++) af[i] = 0.f;

    union U { float4 f; __half2 h[4]; };
    for (int j = s; j < e; j += 16) {
        int i0 = j + grp, i1 = i0 + 4, i2 = i0 + 8, i3 = i0 + 12;
        int s0 = (i0 < e) ? eidx[i0] : -1;
        int s1 = (i1 < e) ? eidx[i1] : -1;
        int s2 = (i2 < e) ? eidx[i2] : -1;
        int s3 = (i3 < e) ? eidx[i3] : -1;
        U u0, u1, u2, u3;
        float n0 = 1.f, n1 = 1.f, n2 = 1.f, n3 = 1.f;
        if (s0 >= 0) u0.f = *(const float4*)&Yh[(size_t)s0 * HID + f0];
        if (s1 >= 0) u1.f = *(const float4*)&Yh[(size_t)s1 * HID + f0];
        if (s2 >= 0) u2.f = *(const float4*)&Yh[(size_t)s2 * HID + f0];
        if (s3 >= 0) u3.f = *(const float4*)&Yh[(size_t)s3 * HID + f0];
        if (NOUTG) {
            if (s0 >= 0) n0 = nout[s0];
            if (s1 >= 0) n1 = nout[s1];
            if (s2 >= 0) n2 = nout[s2];
            if (s3 >= 0) n3 = nout[s3];
        }
        #define ACCUM(S_, U_, N_)                                           \
        if (S_ >= 0) {                                                      \
            _Pragma("unroll")                                               \
            for (int k = 0; k < 4; k++) {                                   \
                float2 f = __half22float2(U_.h[k]);                         \
                if (NOUTG) {                                                \
                    af[2 * k]     = fmaf(N_, f.x, af[2 * k]);               \
                    af[2 * k + 1] = fmaf(N_, f.y, af[2 * k + 1]);           \
                } else {                                                    \
                    af[2 * k] += f.x; af[2 * k + 1] += f.y;                 \
                }                                                           \
            }                                                               \
        }
        ACCUM(s0, u0, n0) ACCUM(s1, u1, n1) ACCUM(s2, u2, n2) ACCUM(s3, u3, n3)
        #undef ACCUM
    }
    #pragma unroll
    for (int i = 0; i < 8; i++) {
        af[i] += __shfl_xor(af[i], 16, 64);
        af[i] += __shfl_xor(af[i], 32, 64);
    }

    float ni = nin[r];
    float4 b0 = *(const float4*)&bias[f0];
    float4 b1 = *(const float4*)&bias[f0 + 4];
    float v[8];
    v[0] = af[0] * ni + b0.x; v[1] = af[1] * ni + b0.y;
    v[2] = af[2] * ni + b0.z; v[3] = af[3] * ni + b0.w;
    v[4] = af[4] * ni + b1.x; v[5] = af[5] * ni + b1.y;
    v[6] = af[6] * ni + b1.z; v[7] = af[7] * ni + b1.w;

    float sum = 0.f;
    #pragma unroll
    for (int i = 0; i < 8; i++) sum += v[i];
    #pragma unroll
    for (int o = 8; o >= 1; o >>= 1) sum += __shfl_xor(sum, o, 64);
    float mu = sum * (1.f / 128.f);

    float d[8], vs = 0.f;
    #pragma unroll
    for (int i = 0; i < 8; i++) { d[i] = v[i] - mu; vs += d[i] * d[i]; }
    #pragma unroll
    for (int o = 8; o >= 1; o >>= 1) vs += __shfl_xor(vs, o, 64);
    float rs = rsqrtf(vs * (1.f / 128.f) + 1e-5f);

    float4 g0 = *(const float4*)&gam[f0];
    float4 g1 = *(const float4*)&gam[f0 + 4];
    float4 e0 = *(const float4*)&bet[f0];
    float4 e1 = *(const float4*)&bet[f0 + 4];
    float x[8];
    x[0] = lrelu(d[0] * rs * g0.x + e0.x);
    x[1] = lrelu(d[1] * rs * g0.y + e0.y);
    x[2] = lrelu(d[2] * rs * g0.z + e0.z);
    x[3] = lrelu(d[3] * rs * g0.w + e0.w);
    x[4] = lrelu(d[4] * rs * g1.x + e1.x);
    x[5] = lrelu(d[5] * rs * g1.y + e1.y);
    x[6] = lrelu(d[6] * rs * g1.z + e1.z);
    x[7] = lrelu(d[7] * rs * g1.w + e1.w);

    if (PROJ) {
        float z0 = 0.f, z1 = 0.f;
        #pragma unroll
        for (int i = 0; i < 8; i++) {
            float2 w3 = *(const float2*)&W3[(f0 + i) * 2];
            z0 = fmaf(x[i], w3.x, z0);
            z1 = fmaf(x[i], w3.y, z1);
        }
        #pragma unroll
        for (int o = 8; o >= 1; o >>= 1) {
            z0 += __shfl_xor(z0, o, 64);
            z1 += __shfl_xor(z1, o, 64);
        }
        if (lane == 0) {
            float no = nout[r];
            *(float2*)&Z[r * 2] = make_float2(z0 * no, z1 * no);
        }
    } else {
        if (grp == 0) {
            union { __half2 h[4]; float4 f; } o;
            o.h[0] = __floats2half2_rn(x[0], x[1]);
            o.h[1] = __floats2half2_rn(x[2], x[3]);
            o.h[2] = __floats2half2_rn(x[4], x[5]);
            o.h[3] = __floats2half2_rn(x[6], x[7]);
            *(float4*)&Xo[(size_t)r * HID + f0] = o.f;
        }
    }
}

// ---------------- GEMM layer 2 (fp16 A, output scaled by norm_out row) ----------------
__global__ __launch_bounds__(256) void gemm2(const _Float16* __restrict__ Xh,
                                             const _Float16* __restrict__ W2sw,
                                             const float* __restrict__ nout,
                                             _Float16* __restrict__ Yh, int n) {
    __shared__ __align__(16) _Float16 Wt[16384];  // 32 KB
    gemm_body<true, true>(Xh, W2sw, nout, Yh, blockIdx.x * 64, n, Wt);
}

// ---------------- final aggregation (2 dims), 4-way unrolled ----------------
__global__ void agg3(const float* __restrict__ Z, const int* __restrict__ off,
                     const int* __restrict__ eidx, const float* __restrict__ nin,
                     const float* __restrict__ b3, float* __restrict__ out, int n) {
    int r = blockIdx.x * blockDim.x + threadIdx.x;
    if (r < n) {
        int s = off[r], e = off[r + 1];
        float p0 = 0.f, p1 = 0.f, q0 = 0.f, q1 = 0.f;
        float u0 = 0.f, u1 = 0.f, w0 = 0.f, w1 = 0.f;
        int j = s;
        for (; j + 3 < e; j += 4) {
            float2 v0 = *(const float2*)&Z[eidx[j] * 2];
            float2 v1 = *(const float2*)&Z[eidx[j + 1] * 2];
            float2 v2 = *(const float2*)&Z[eidx[j + 2] * 2];
            float2 v3 = *(const float2*)&Z[eidx[j + 3] * 2];
            p0 += v0.x; p1 += v0.y;
            q0 += v1.x; q1 += v1.y;
            u0 += v2.x; u1 += v2.y;
            w0 += v3.x; w1 += v3.y;
        }
        for (; j < e; ++j) {
            float2 v = *(const float2*)&Z[eidx[j] * 2];
            p0 += v.x; p1 += v.y;
        }
        float a0 = (p0 + q0) + (u0 + w0);
        float a1 = (p1 + q1) + (u1 + w1);
        float ni = nin[r];
        out[r * 2 + 0] = a0 * ni + b3[0];
        out[r * 2 + 1] = a1 * ni + b3[1];
    }
}

extern "C" void kernel_launch(void* const* d_in, const int* in_sizes, int n_in,
                              void* d_out, int out_size, void* d_ws, size_t ws_size,
                              hipStream_t stream) {
    const float* feat = (const float*)d_in[0];
    const int* src = (const int*)d_in[1];
    const int* dst = (const int*)d_in[2];
    const float* W1 = (const float*)d_in[3];
    const float* b1 = (const float*)d_in[4];
    const float* W2 = (const float*)d_in[5];
    const float* b2 = (const float*)d_in[6];
    const float* W3 = (const float*)d_in[7];
    const float* b3 = (const float*)d_in[8];
    const float* g1 = (const float*)d_in[9];
    const float* be1 = (const float*)d_in[10];
    const float* g2 = (const float*)d_in[11];
    const float* be2 = (const float*)d_in[12];
    float* out = (float*)d_out;

    char* p = (char*)d_ws;
    auto carve = [&](size_t bytes) -> char* {
        char* q = p;
        p += (bytes + 255) & ~(size_t)255;
        return q;
    };
    int* deg_out = (int*)carve(NN * 4);
    int* deg_in  = (int*)carve(NN * 4);
    float* norm_out = (float*)carve(NN * 4);
    float* norm_in  = (float*)carve(NN * 4);
    int* off     = (int*)carve((NN + 1) * 4);
    int* bsums   = (int*)carve(64 * 4);
    int* boff    = (int*)carve(64 * 4);
    int* eidx    = (int*)carve((size_t)NE * 4);
    unsigned short* rank_local = (unsigned short*)carve((size_t)NE * 2);
    int* H_in  = (int*)carve((size_t)HB * 4096 * 4);   // 16 MB (becomes P in-place; Xh aliases after fill)
    int* H_out = (int*)carve((size_t)HB * 4096 * 4);   // 16 MB (dead after prefix_k; Z aliases)
    _Float16* W1sw = (_Float16*)carve(16384 * 2);
    _Float16* W2sw = (_Float16*)carve(16384 * 2);
    _Float16* Yh = (_Float16*)carve((size_t)NN * HID * 2);
    // aliases into dead H buffers (stream-ordered: H_in dead after fill_kernel, H_out after prefix_k)
    __half* Xh = (__half*)H_in;                        // 12.8 MB <= 16 MB
    float* Z = (float*)H_out;                          // 0.4 MB

    convW2<<<128, 256, 0, stream>>>(W1, W2, W1sw, W2sw);

    // LDS-privatized degree histograms + local ranks || MFMA GEMM-1 (no global atomics)
    mega_h1<<<HB + GEMMB, 256, 0, stream>>>(feat, W1sw, Yh, src, dst, rank_local, H_in, H_out, NN);

    // exclusive prefix over slices (P in-place in H_in) + final degrees
    prefix_k<<<128, 256, 0, stream>>>(H_in, H_out, deg_in, deg_out);

    // scan trio (scan1 fused with norms)
    int nb = (NN + 1023) / 1024;  // 49
    scan1<<<nb, 1024, 0, stream>>>(deg_in, deg_out, off, bsums, norm_out, norm_in, NN);
    scan2<<<1, 64, 0, stream>>>(bsums, boff, nb, off + NN);
    scan3<<<nb, 1024, 0, stream>>>(off, boff, NN);

    // CSR fill (atomic-free)
    fill_kernel<<<(NE + 255) / 256, 256, 0, stream>>>(src, dst, off, rank_local, H_in, eidx, NE);

    // layer 1 aggregation (folds nout[src]) -> fp16 X (aliased onto H_in)
    agg_post<false, true><<<(NN + 3) / 4, 256, 0, stream>>>((const __half*)Yh, off, eidx, norm_out, norm_in,
                                                            b1, g1, be1, Xh, nullptr, nullptr, NN);
    // layer 2 GEMM (fp16 MFMA, output pre-scaled by norm_out)
    gemm2<<<GEMMB, 256, 0, stream>>>((const _Float16*)Xh, W2sw, norm_out, Yh, NN);
    // layer 2 aggregation (Yh pre-scaled) fused with layer-3 projection -> Z (aliased onto H_out)
    agg_post<true, false><<<(NN + 3) / 4, 256, 0, stream>>>((const __half*)Yh, off, eidx, norm_out, norm_in,
                                                            b2, g2, be2, nullptr, W3, Z, NN);
    // layer 3 aggregation -> out
    agg3<<<(NN + 255) / 256, 256, 0, stream>>>(Z, off, eidx, norm_in, b3, out, NN);
}

// Round 13
// 155.852 us; speedup vs baseline: 1.0806x; 1.0580x over previous
//
#include <hip/hip_runtime.h>
#include <hip/hip_fp16.h>

#define NN 50000
#define NE 800000
#define HID 128
#define NSL 128                      // edge slices
#define EPS (NE / NSL)               // 6250 edges per slice
#define NRG 2                        // node ranges of 32768
#define HB  (NRG * NSL)              // 256 histogram blocks
#define PLW 8192                     // packed words (ints) per (slice,range) plane: 32768 nodes / 4
#define GEMMB ((NN + 63) / 64)       // 64 rows per block

typedef _Float16 f16x8 __attribute__((ext_vector_type(8)));
typedef float f32x4 __attribute__((ext_vector_type(4)));

static __device__ __forceinline__ float lrelu(float x) { return x > 0.f ? x : 0.01f * x; }

// ------- hist_k: blocks [0,HB): 8-bit LDS degree histograms + per-slice rank;
//         blocks [HB, HB+128): W converter (fp32 -> transposed pre-swizzled fp16) -------
__global__ __launch_bounds__(256) void hist_k(const int* __restrict__ src, const int* __restrict__ dst,
                                              unsigned char* __restrict__ rank_local,
                                              int* __restrict__ H_in, int* __restrict__ H_out,
                                              const float* __restrict__ W1, const float* __restrict__ W2,
                                              _Float16* __restrict__ W1o, _Float16* __restrict__ W2o) {
    __shared__ __align__(16) int lds[2 * PLW];       // 64 KB: hin | hout (8-bit packed x4)
    int b = blockIdx.x, t = threadIdx.x;
    if (b >= HB) {
        int i = (b - HB) * 256 + t;                  // 0..32767
        const float* W = (i < 16384) ? W1 : W2;
        _Float16* O = (i < 16384) ? W1o : W2o;
        int j = i & 16383;
        int p = j * 2;
        int q = p ^ (((p >> 8) & 7) << 4);
        int c = q >> 8;
        int k = (q & 255) >> 1;
        O[j] = (_Float16)W[k * 128 + c];
        return;
    }
    int r = b & 1, s = b >> 1;
    #pragma unroll
    for (int i = t; i < (2 * PLW) / 4; i += 256) ((int4*)lds)[i] = make_int4(0, 0, 0, 0);
    __syncthreads();
    int* hin  = lds;            // dst counts for range r (4 x 8-bit per int)
    int* hout = lds + PLW;      // src counts
    int e0 = s * EPS;
    for (int i = t; i < EPS; i += 256) {
        int e = e0 + i;
        int sd = src[e];
        int dd = dst[e];
        if ((sd >> 15) == r) atomicAdd(&hout[(sd & 32767) >> 2], 1 << ((sd & 3) << 3));
        if ((dd >> 15) == r) {
            int old = atomicAdd(&hin[(dd & 32767) >> 2], 1 << ((dd & 3) << 3));
            rank_local[e] = (unsigned char)((old >> ((dd & 3) << 3)) & 0xff);
        }
    }
    __syncthreads();
    // slice-major planes: plane index (s*2 + r)
    int4* gi = (int4*)(H_in  + (size_t)(s * 2 + r) * PLW);
    int4* go = (int4*)(H_out + (size_t)(s * 2 + r) * PLW);
    #pragma unroll
    for (int i = t; i < PLW / 4; i += 256) {
        gi[i] = ((int4*)hin)[i];
        go[i] = ((int4*)hout)[i];
    }
}

// ---------------- MFMA GEMM body (32 KB LDS) ----------------
template <bool AF16, bool SCALE>
static __device__ __forceinline__ void gemm_body(const void* __restrict__ A,
                                                 const _Float16* __restrict__ Wsw,
                                                 const float* __restrict__ nout,
                                                 _Float16* __restrict__ Y, int r0, int n,
                                                 _Float16* Wt) {
    int t = threadIdx.x;
    #pragma unroll
    for (int i = 0; i < 8; i++) {
        int idx = t + i * 256;
        *(((float4*)Wt) + idx) = ((const float4*)Wsw)[idx];
    }
    int wid = t >> 6, lane = t & 63;
    int kgrp = lane >> 4, l15 = lane & 15;

    int r = r0 + wid * 16 + l15;
    f16x8 a[4];
    #pragma unroll
    for (int ks = 0; ks < 4; ks++)
        #pragma unroll
        for (int j = 0; j < 8; j++) a[ks][j] = (_Float16)0.f;
    if (r < n) {
        if (AF16) {
            const _Float16* Ah = (const _Float16*)A + (size_t)r * HID + kgrp * 8;
            #pragma unroll
            for (int ks = 0; ks < 4; ks++) a[ks] = *(const f16x8*)(Ah + ks * 32);
        } else {
            const float* Af = (const float*)A + (size_t)r * HID + kgrp * 8;
            #pragma unroll
            for (int ks = 0; ks < 4; ks++) {
                float4 lo = *(const float4*)(Af + ks * 32);
                float4 hi = *(const float4*)(Af + ks * 32 + 4);
                a[ks][0] = (_Float16)lo.x; a[ks][1] = (_Float16)lo.y;
                a[ks][2] = (_Float16)lo.z; a[ks][3] = (_Float16)lo.w;
                a[ks][4] = (_Float16)hi.x; a[ks][5] = (_Float16)hi.y;
                a[ks][6] = (_Float16)hi.z; a[ks][7] = (_Float16)hi.w;
            }
        }
    }
    __syncthreads();

    f32x4 acc[8];
    #pragma unroll
    for (int td = 0; td < 8; td++)
        #pragma unroll
        for (int j = 0; j < 4; j++) acc[td][j] = 0.f;

    const char* base = (const char*)Wt;
    #pragma unroll
    for (int ks = 0; ks < 4; ks++) {
        #pragma unroll
        for (int td = 0; td < 8; td++) {
            int c = td * 16 + l15;
            int addr = ((c << 8) + 64 * ks + 16 * kgrp) ^ ((c & 7) << 4);
            f16x8 bfr = *(const f16x8*)(base + addr);
            acc[td] = __builtin_amdgcn_mfma_f32_16x16x32_f16(a[ks], bfr, acc[td], 0, 0, 0);
        }
    }

    int ro = r0 + wid * 16 + kgrp * 4;   // C/D: col = lane&15, row = (lane>>4)*4 + reg
    float no[4] = {1.f, 1.f, 1.f, 1.f};
    if (SCALE) {
        #pragma unroll
        for (int reg = 0; reg < 4; reg++) {
            int orow = ro + reg;
            if (orow < n) no[reg] = nout[orow];
        }
    }
    #pragma unroll
    for (int td = 0; td < 8; td++) {
        #pragma unroll
        for (int reg = 0; reg < 4; reg++) {
            int orow = ro + reg;
            if (orow < n) Y[(size_t)orow * HID + td * 16 + l15] = (_Float16)(acc[td][reg] * no[reg]);
        }
    }
}

// ---------------- GEMM layer 1 (fp32 A, unscaled out) ----------------
__global__ __launch_bounds__(256) void gemm1(const float* __restrict__ feat,
                                             const _Float16* __restrict__ W1sw,
                                             _Float16* __restrict__ Yh, int n) {
    __shared__ __align__(16) _Float16 Wt[16384];
    gemm_body<false, false>(feat, W1sw, nullptr, Yh, blockIdx.x * 64, n, Wt);
}

// ---------------- GEMM layer 2 (fp16 A, out scaled by norm_out row) ----------------
__global__ __launch_bounds__(256) void gemm2(const _Float16* __restrict__ Xh,
                                             const _Float16* __restrict__ W2sw,
                                             const float* __restrict__ nout,
                                             _Float16* __restrict__ Yh, int n) {
    __shared__ __align__(16) _Float16 Wt[16384];
    gemm_body<true, true>(Xh, W2sw, nout, Yh, blockIdx.x * 64, n, Wt);
}

// ---- prefix_k: packed-byte exclusive prefix over slices (in-place -> P) + degrees + norms ----
__global__ void prefix_k(int* __restrict__ H_in, const int* __restrict__ H_out,
                         int* __restrict__ deg_in,
                         float* __restrict__ norm_in, float* __restrict__ norm_out) {
    int tid = blockIdx.x * 256 + threadIdx.x;   // 0..16383
    int r = tid >> 13, w = tid & 8191;
    int runIn = 0, runOut = 0;                  // packed 4x8-bit sums (deg <= ~50, no byte carry)
    for (int s = 0; s < NSL; s++) {
        size_t idx = ((size_t)(s * 2 + r) << 13) + w;
        int hv = H_in[idx];
        H_in[idx] = runIn;                      // packed exclusive prefix
        runIn += hv;
        runOut += H_out[idx];
    }
    #pragma unroll
    for (int k = 0; k < 4; k++) {
        int n = (r << 15) | (w << 2) | k;
        if (n < NN) {
            int di = (runIn >> (k * 8)) & 0xff;
            int dо = (runOut >> (k * 8)) & 0xff;
            deg_in[n] = di;
            norm_in[n]  = rsqrtf((float)max(di, 1));
            norm_out[n] = rsqrtf((float)max(dо, 1));
        }
    }
}

// ---------------- prefix scan trio over deg_in ----------------
__global__ void scan1(const int* __restrict__ deg_in,
                      int* __restrict__ excl, int* __restrict__ bsums, int n) {
    __shared__ int ws[16];
    int t = threadIdx.x;
    int i = blockIdx.x * 1024 + t;
    int v = (i < n) ? deg_in[i] : 0;
    int x = v;
    #pragma unroll
    for (int o = 1; o < 64; o <<= 1) {
        int y = __shfl_up(x, o, 64);
        if ((t & 63) >= o) x += y;
    }
    if ((t & 63) == 63) ws[t >> 6] = x;
    __syncthreads();
    if (t < 16) {
        int s = ws[t];
        #pragma unroll
        for (int o = 1; o < 16; o <<= 1) {
            int y = __shfl_up(s, o, 16);
            if (t >= o) s += y;
        }
        ws[t] = s;
    }
    __syncthreads();
    int wid = t >> 6;
    int pre = wid ? ws[wid - 1] : 0;
    if (i < n) excl[i] = pre + x - v;
    if (t == 1023) bsums[blockIdx.x] = ws[15];
}

__global__ void scan2(const int* __restrict__ bsums, int* __restrict__ boff, int nb,
                      int* __restrict__ total_out) {
    int t = threadIdx.x;
    int v = (t < nb) ? bsums[t] : 0;
    int x = v;
    #pragma unroll
    for (int o = 1; o < 64; o <<= 1) {
        int y = __shfl_up(x, o, 64);
        if (t >= o) x += y;
    }
    if (t < nb) boff[t] = x - v;
    if (t == 63) total_out[0] = x;
}

__global__ void scan3(int* __restrict__ off, const int* __restrict__ boff, int n) {
    int i = blockIdx.x * 1024 + threadIdx.x;
    if (i < n) off[i] += boff[blockIdx.x];
}

// ---------------- CSR fill: atomic-free (u8 local rank + slice-major 8-bit P) ----------------
__global__ void fill_kernel(const int* __restrict__ src, const int* __restrict__ dst,
                            const int* __restrict__ off, const unsigned char* __restrict__ rank_local,
                            const int* __restrict__ P, int* __restrict__ eidx, int E) {
    int e = blockIdx.x * blockDim.x + threadIdx.x;
    if (e < E) {
        int dd = dst[e];
        int s = e / EPS;
        size_t idx = ((size_t)(s * 2 + (dd >> 15)) << 13) + ((dd & 32767) >> 2);
        int pv = (P[idx] >> ((dd & 3) << 3)) & 0xff;
        eidx[off[dd] + (int)rank_local[e] + pv] = src[e];
    }
}

// ---- fused aggregate (depth-4 fp16 gather) + nin + bias + LN + LeakyReLU ----
template <bool PROJ, bool NOUTG>
__global__ __launch_bounds__(256) void agg_post(const __half* __restrict__ Yh, const int* __restrict__ off,
                                                const int* __restrict__ eidx, const float* __restrict__ nout,
                                                const float* __restrict__ nin,
                                                const float* __restrict__ bias, const float* __restrict__ gam,
                                                const float* __restrict__ bet, __half* __restrict__ Xo,
                                                const float* __restrict__ W3, float* __restrict__ Z, int n) {
    int w = threadIdx.x >> 6, lane = threadIdx.x & 63;
    int r = blockIdx.x * 4 + w;
    if (r >= n) return;
    int grp = lane >> 4;
    int f0 = (lane & 15) * 8;
    int s = off[r], e = off[r + 1];

    float af[8];
    #pragma unroll
    for (int i = 0; i < 8; i++) af[i] = 0.f;

    union U { float4 f; __half2 h[4]; };
    for (int j = s; j < e; j += 16) {
        int i0 = j + grp, i1 = i0 + 4, i2 = i0 + 8, i3 = i0 + 12;
        int s0 = (i0 < e) ? eidx[i0] : -1;
        int s1 = (i1 < e) ? eidx[i1] : -1;
        int s2 = (i2 < e) ? eidx[i2] : -1;
        int s3 = (i3 < e) ? eidx[i3] : -1;
        U u0, u1, u2, u3;
        float n0 = 1.f, n1 = 1.f, n2 = 1.f, n3 = 1.f;
        if (s0 >= 0) u0.f = *(const float4*)&Yh[(size_t)s0 * HID + f0];
        if (s1 >= 0) u1.f = *(const float4*)&Yh[(size_t)s1 * HID + f0];
        if (s2 >= 0) u2.f = *(const float4*)&Yh[(size_t)s2 * HID + f0];
        if (s3 >= 0) u3.f = *(const float4*)&Yh[(size_t)s3 * HID + f0];
        if (NOUTG) {
            if (s0 >= 0) n0 = nout[s0];
            if (s1 >= 0) n1 = nout[s1];
            if (s2 >= 0) n2 = nout[s2];
            if (s3 >= 0) n3 = nout[s3];
        }
        #define ACCUM(S_, U_, N_)                                           \
        if (S_ >= 0) {                                                      \
            _Pragma("unroll")                                               \
            for (int k = 0; k < 4; k++) {                                   \
                float2 f = __half22float2(U_.h[k]);                         \
                if (NOUTG) {                                                \
                    af[2 * k]     = fmaf(N_, f.x, af[2 * k]);               \
                    af[2 * k + 1] = fmaf(N_, f.y, af[2 * k + 1]);           \
                } else {                                                    \
                    af[2 * k] += f.x; af[2 * k + 1] += f.y;                 \
                }                                                           \
            }                                                               \
        }
        ACCUM(s0, u0, n0) ACCUM(s1, u1, n1) ACCUM(s2, u2, n2) ACCUM(s3, u3, n3)
        #undef ACCUM
    }
    #pragma unroll
    for (int i = 0; i < 8; i++) {
        af[i] += __shfl_xor(af[i], 16, 64);
        af[i] += __shfl_xor(af[i], 32, 64);
    }

    float ni = nin[r];
    float4 b0 = *(const float4*)&bias[f0];
    float4 b1 = *(const float4*)&bias[f0 + 4];
    float v[8];
    v[0] = af[0] * ni + b0.x; v[1] = af[1] * ni + b0.y;
    v[2] = af[2] * ni + b0.z; v[3] = af[3] * ni + b0.w;
    v[4] = af[4] * ni + b1.x; v[5] = af[5] * ni + b1.y;
    v[6] = af[6] * ni + b1.z; v[7] = af[7] * ni + b1.w;

    float sum = 0.f;
    #pragma unroll
    for (int i = 0; i < 8; i++) sum += v[i];
    #pragma unroll
    for (int o = 8; o >= 1; o >>= 1) sum += __shfl_xor(sum, o, 64);
    float mu = sum * (1.f / 128.f);

    float d[8], vs = 0.f;
    #pragma unroll
    for (int i = 0; i < 8; i++) { d[i] = v[i] - mu; vs += d[i] * d[i]; }
    #pragma unroll
    for (int o = 8; o >= 1; o >>= 1) vs += __shfl_xor(vs, o, 64);
    float rs = rsqrtf(vs * (1.f / 128.f) + 1e-5f);

    float4 g0 = *(const float4*)&gam[f0];
    float4 g1 = *(const float4*)&gam[f0 + 4];
    float4 e0 = *(const float4*)&bet[f0];
    float4 e1 = *(const float4*)&bet[f0 + 4];
    float x[8];
    x[0] = lrelu(d[0] * rs * g0.x + e0.x);
    x[1] = lrelu(d[1] * rs * g0.y + e0.y);
    x[2] = lrelu(d[2] * rs * g0.z + e0.z);
    x[3] = lrelu(d[3] * rs * g0.w + e0.w);
    x[4] = lrelu(d[4] * rs * g1.x + e1.x);
    x[5] = lrelu(d[5] * rs * g1.y + e1.y);
    x[6] = lrelu(d[6] * rs * g1.z + e1.z);
    x[7] = lrelu(d[7] * rs * g1.w + e1.w);

    if (PROJ) {
        float z0 = 0.f, z1 = 0.f;
        #pragma unroll
        for (int i = 0; i < 8; i++) {
            float2 w3 = *(const float2*)&W3[(f0 + i) * 2];
            z0 = fmaf(x[i], w3.x, z0);
            z1 = fmaf(x[i], w3.y, z1);
        }
        #pragma unroll
        for (int o = 8; o >= 1; o >>= 1) {
            z0 += __shfl_xor(z0, o, 64);
            z1 += __shfl_xor(z1, o, 64);
        }
        if (lane == 0) {
            float no = nout[r];
            *(float2*)&Z[r * 2] = make_float2(z0 * no, z1 * no);
        }
    } else {
        if (grp == 0) {
            union { __half2 h[4]; float4 f; } o;
            o.h[0] = __floats2half2_rn(x[0], x[1]);
            o.h[1] = __floats2half2_rn(x[2], x[3]);
            o.h[2] = __floats2half2_rn(x[4], x[5]);
            o.h[3] = __floats2half2_rn(x[6], x[7]);
            *(float4*)&Xo[(size_t)r * HID + f0] = o.f;
        }
    }
}

// ---------------- final aggregation (2 dims), 4-way unrolled ----------------
__global__ void agg3(const float* __restrict__ Z, const int* __restrict__ off,
                     const int* __restrict__ eidx, const float* __restrict__ nin,
                     const float* __restrict__ b3, float* __restrict__ out, int n) {
    int r = blockIdx.x * blockDim.x + threadIdx.x;
    if (r < n) {
        int s = off[r], e = off[r + 1];
        float p0 = 0.f, p1 = 0.f, q0 = 0.f, q1 = 0.f;
        float u0 = 0.f, u1 = 0.f, w0 = 0.f, w1 = 0.f;
        int j = s;
        for (; j + 3 < e; j += 4) {
            float2 v0 = *(const float2*)&Z[eidx[j] * 2];
            float2 v1 = *(const float2*)&Z[eidx[j + 1] * 2];
            float2 v2 = *(const float2*)&Z[eidx[j + 2] * 2];
            float2 v3 = *(const float2*)&Z[eidx[j + 3] * 2];
            p0 += v0.x; p1 += v0.y;
            q0 += v1.x; q1 += v1.y;
            u0 += v2.x; u1 += v2.y;
            w0 += v3.x; w1 += v3.y;
        }
        for (; j < e; ++j) {
            float2 v = *(const float2*)&Z[eidx[j] * 2];
            p0 += v.x; p1 += v.y;
        }
        float a0 = (p0 + q0) + (u0 + w0);
        float a1 = (p1 + q1) + (u1 + w1);
        float ni = nin[r];
        out[r * 2 + 0] = a0 * ni + b3[0];
        out[r * 2 + 1] = a1 * ni + b3[1];
    }
}

extern "C" void kernel_launch(void* const* d_in, const int* in_sizes, int n_in,
                              void* d_out, int out_size, void* d_ws, size_t ws_size,
                              hipStream_t stream) {
    const float* feat = (const float*)d_in[0];
    const int* src = (const int*)d_in[1];
    const int* dst = (const int*)d_in[2];
    const float* W1 = (const float*)d_in[3];
    const float* b1 = (const float*)d_in[4];
    const float* W2 = (const float*)d_in[5];
    const float* b2 = (const float*)d_in[6];
    const float* W3 = (const float*)d_in[7];
    const float* b3 = (const float*)d_in[8];
    const float* g1 = (const float*)d_in[9];
    const float* be1 = (const float*)d_in[10];
    const float* g2 = (const float*)d_in[11];
    const float* be2 = (const float*)d_in[12];
    float* out = (float*)d_out;

    char* p = (char*)d_ws;
    auto carve = [&](size_t bytes) -> char* {
        char* q = p;
        p += (bytes + 255) & ~(size_t)255;
        return q;
    };
    int* deg_in  = (int*)carve(NN * 4);
    float* norm_out = (float*)carve(NN * 4);
    float* norm_in  = (float*)carve(NN * 4);
    int* off     = (int*)carve((NN + 1) * 4);
    int* bsums   = (int*)carve(64 * 4);
    int* boff    = (int*)carve(64 * 4);
    int* eidx    = (int*)carve((size_t)NE * 4);
    unsigned char* rank_local = (unsigned char*)carve((size_t)NE);
    int* H_in  = (int*)carve((size_t)NSL * NRG * PLW * 4);   // 8 MB, slice-major; becomes P in-place
    int* H_out = (int*)carve((size_t)NSL * NRG * PLW * 4);   // 8 MB
    _Float16* W1sw = (_Float16*)carve(16384 * 2);
    _Float16* W2sw = (_Float16*)carve(16384 * 2);
    _Float16* Yh = (_Float16*)carve((size_t)NN * HID * 2);
    __half* Xh = (__half*)carve((size_t)NN * HID * 2);
    float* Z = (float*)carve((size_t)NN * 2 * 4);

    // 8-bit degree histograms + per-slice ranks; blocks >= HB convert W1/W2
    hist_k<<<HB + 128, 256, 0, stream>>>(src, dst, rank_local, H_in, H_out, W1, W2, W1sw, W2sw);

    // MFMA GEMM-1 (unnormalized feat @ W1 -> fp16)
    gemm1<<<GEMMB, 256, 0, stream>>>(feat, W1sw, Yh, NN);

    // packed-byte exclusive prefix over slices (P in-place) + degrees + norms
    prefix_k<<<64, 256, 0, stream>>>(H_in, H_out, deg_in, norm_in, norm_out);

    // scan trio over deg_in -> off
    int nb = (NN + 1023) / 1024;  // 49
    scan1<<<nb, 1024, 0, stream>>>(deg_in, off, bsums, NN);
    scan2<<<1, 64, 0, stream>>>(bsums, boff, nb, off + NN);
    scan3<<<nb, 1024, 0, stream>>>(off, boff, NN);

    // CSR fill (atomic-free, slice-major P window per block)
    fill_kernel<<<(NE + 255) / 256, 256, 0, stream>>>(src, dst, off, rank_local, H_in, eidx, NE);

    // layer 1 aggregation (folds nout[src]) -> fp16 X
    agg_post<false, true><<<(NN + 3) / 4, 256, 0, stream>>>((const __half*)Yh, off, eidx, norm_out, norm_in,
                                                            b1, g1, be1, Xh, nullptr, nullptr, NN);
    // layer 2 GEMM (fp16 MFMA, output pre-scaled by norm_out)
    gemm2<<<GEMMB, 256, 0, stream>>>((const _Float16*)Xh, W2sw, norm_out, Yh, NN);
    // layer 2 aggregation (Yh pre-scaled) fused with layer-3 projection -> Z
    agg_post<true, false><<<(NN + 3) / 4, 256, 0, stream>>>((const __half*)Yh, off, eidx, norm_out, norm_in,
                                                            b2, g2, be2, nullptr, W3, Z, NN);
    // layer 3 aggregation -> out
    agg3<<<(NN + 255) / 256, 256, 0, stream>>>(Z, off, eidx, norm_in, b3, out, NN);
}

// Round 14
// 150.013 us; speedup vs baseline: 1.1226x; 1.0389x over previous
//
#include <hip/hip_runtime.h>
#include <hip/hip_fp16.h>

#define NN 50000
#define NE 800000
#define HID 128
#define NSL 128                      // edge slices
#define EPS (NE / NSL)               // 6250 edges per slice
#define NRG 4                        // node ranges of 16384
#define HB  (NRG * NSL)              // 512 histogram blocks
#define PLW 4096                     // packed words (ints) per (slice,range) plane: 16384 nodes / 4
#define GEMMB ((NN + 63) / 64)       // 782 gemm blocks (64 rows each)

typedef _Float16 f16x8 __attribute__((ext_vector_type(8)));
typedef float f32x4 __attribute__((ext_vector_type(4)));

static __device__ __forceinline__ float lrelu(float x) { return x > 0.f ? x : 0.01f * x; }

// ---------------- MFMA GEMM compute (Wt already staged+swizzled in LDS; caller syncs) ----------------
template <bool AF16, bool SCALE>
static __device__ __forceinline__ void gemm_compute(const void* __restrict__ A,
                                                    const float* __restrict__ nout,
                                                    _Float16* __restrict__ Y, int r0, int n,
                                                    const _Float16* Wt) {
    int t = threadIdx.x;
    int wid = t >> 6, lane = t & 63;
    int kgrp = lane >> 4, l15 = lane & 15;

    int r = r0 + wid * 16 + l15;
    f16x8 a[4];
    #pragma unroll
    for (int ks = 0; ks < 4; ks++)
        #pragma unroll
        for (int j = 0; j < 8; j++) a[ks][j] = (_Float16)0.f;
    if (r < n) {
        if (AF16) {
            const _Float16* Ah = (const _Float16*)A + (size_t)r * HID + kgrp * 8;
            #pragma unroll
            for (int ks = 0; ks < 4; ks++) a[ks] = *(const f16x8*)(Ah + ks * 32);
        } else {
            const float* Af = (const float*)A + (size_t)r * HID + kgrp * 8;
            #pragma unroll
            for (int ks = 0; ks < 4; ks++) {
                float4 lo = *(const float4*)(Af + ks * 32);
                float4 hi = *(const float4*)(Af + ks * 32 + 4);
                a[ks][0] = (_Float16)lo.x; a[ks][1] = (_Float16)lo.y;
                a[ks][2] = (_Float16)lo.z; a[ks][3] = (_Float16)lo.w;
                a[ks][4] = (_Float16)hi.x; a[ks][5] = (_Float16)hi.y;
                a[ks][6] = (_Float16)hi.z; a[ks][7] = (_Float16)hi.w;
            }
        }
    }
    __syncthreads();

    f32x4 acc[8];
    #pragma unroll
    for (int td = 0; td < 8; td++)
        #pragma unroll
        for (int j = 0; j < 4; j++) acc[td][j] = 0.f;

    const char* base = (const char*)Wt;
    #pragma unroll
    for (int ks = 0; ks < 4; ks++) {
        #pragma unroll
        for (int td = 0; td < 8; td++) {
            int c = td * 16 + l15;
            int addr = ((c << 8) + 64 * ks + 16 * kgrp) ^ ((c & 7) << 4);
            f16x8 bfr = *(const f16x8*)(base + addr);
            acc[td] = __builtin_amdgcn_mfma_f32_16x16x32_f16(a[ks], bfr, acc[td], 0, 0, 0);
        }
    }

    int ro = r0 + wid * 16 + kgrp * 4;   // C/D: col = lane&15, row = (lane>>4)*4 + reg
    float no[4] = {1.f, 1.f, 1.f, 1.f};
    if (SCALE) {
        #pragma unroll
        for (int reg = 0; reg < 4; reg++) {
            int orow = ro + reg;
            if (orow < n) no[reg] = nout[orow];
        }
    }
    #pragma unroll
    for (int td = 0; td < 8; td++) {
        #pragma unroll
        for (int reg = 0; reg < 4; reg++) {
            int orow = ro + reg;
            if (orow < n) Y[(size_t)orow * HID + td * 16 + l15] = (_Float16)(acc[td][reg] * no[reg]);
        }
    }
}

// ------- phase1: blocks [0,HB): 8-bit LDS degree histograms + per-slice rank;
//         blocks [HB,HB+64): convert W2 -> W2sw;
//         blocks [HB+64,...): GEMM-1 with self-converted W1 (no dependency on converter) -------
__global__ __launch_bounds__(256) void phase1(const int* __restrict__ src, const int* __restrict__ dst,
                                              unsigned char* __restrict__ rank_local,
                                              int* __restrict__ H_in, int* __restrict__ H_out,
                                              const float* __restrict__ W1, const float* __restrict__ W2,
                                              _Float16* __restrict__ W2o,
                                              const float* __restrict__ feat, _Float16* __restrict__ Yh,
                                              int n) {
    __shared__ __align__(16) int lds[2 * PLW];       // 32 KB slab (hist: hin|hout; gemm: W tile)
    int b = blockIdx.x, t = threadIdx.x;
    if (b < HB) {
        int r = b & 3, s = b >> 2;
        #pragma unroll
        for (int i = t; i < (2 * PLW) / 4; i += 256) ((int4*)lds)[i] = make_int4(0, 0, 0, 0);
        __syncthreads();
        int* hin  = lds;            // dst counts for range r (4 x 8-bit per int)
        int* hout = lds + PLW;      // src counts
        int e0 = s * EPS;
        for (int i = t; i < EPS; i += 256) {
            int e = e0 + i;
            int sd = src[e];
            int dd = dst[e];
            if ((sd >> 14) == r) atomicAdd(&hout[(sd & 16383) >> 2], 1 << ((sd & 3) << 3));
            if ((dd >> 14) == r) {
                int old = atomicAdd(&hin[(dd & 16383) >> 2], 1 << ((dd & 3) << 3));
                rank_local[e] = (unsigned char)((old >> ((dd & 3) << 3)) & 0xff);
            }
        }
        __syncthreads();
        // slice-major planes: plane index (s*NRG + r)
        int4* gi = (int4*)(H_in  + (size_t)(s * NRG + r) * PLW);
        int4* go = (int4*)(H_out + (size_t)(s * NRG + r) * PLW);
        #pragma unroll
        for (int i = t; i < PLW / 4; i += 256) {
            gi[i] = ((int4*)hin)[i];
            go[i] = ((int4*)hout)[i];
        }
        return;
    }
    if (b < HB + 64) {
        int j = (b - HB) * 256 + t;                  // 0..16383: W2 -> transposed pre-swizzled fp16
        int p = j * 2;
        int q = p ^ (((p >> 8) & 7) << 4);
        int c = q >> 8;
        int k = (q & 255) >> 1;
        W2o[j] = (_Float16)W2[k * 128 + c];
        return;
    }
    // ---- GEMM-1 with in-block W1 conversion (coalesced fp32 reads, scattered 2B LDS writes) ----
    _Float16* Wt = (_Float16*)lds;
    #pragma unroll
    for (int i = 0; i < 64; i++) {
        int m = t + i * 256;                         // source linear idx: k = m>>7, c = m&127
        int k = m >> 7, c = m & 127;
        int q = (c << 8) | (k << 1);
        int p = q ^ (((q >> 8) & 7) << 4);
        Wt[p >> 1] = (_Float16)W1[m];
    }
    gemm_compute<false, false>(feat, nullptr, Yh, (b - HB - 64) * 64, n, Wt);
}

// ---------------- GEMM layer 2 (fp16 A, out scaled by norm_out row; stages W2sw) ----------------
__global__ __launch_bounds__(256) void gemm2(const _Float16* __restrict__ Xh,
                                             const _Float16* __restrict__ W2sw,
                                             const float* __restrict__ nout,
                                             _Float16* __restrict__ Yh, int n) {
    __shared__ __align__(16) _Float16 Wt[16384];
    int t = threadIdx.x;
    #pragma unroll
    for (int i = 0; i < 8; i++) {
        int idx = t + i * 256;
        *(((float4*)Wt) + idx) = ((const float4*)W2sw)[idx];
    }
    gemm_compute<true, true>(Xh, nout, Yh, blockIdx.x * 64, n, Wt);
}

// ---- prefix_k: packed-byte exclusive prefix over slices (in-place -> P) + degrees + norms ----
__global__ void prefix_k(int* __restrict__ H_in, const int* __restrict__ H_out,
                         int* __restrict__ deg_in,
                         float* __restrict__ norm_in, float* __restrict__ norm_out) {
    int tid = blockIdx.x * 256 + threadIdx.x;   // 0..16383
    int r = tid >> 12, w = tid & 4095;
    int runIn = 0, runOut = 0;                  // packed 4x8-bit sums (deg <= ~50, no byte carry)
    for (int s = 0; s < NSL; s++) {
        size_t idx = ((size_t)(s * NRG + r) << 12) + w;
        int hv = H_in[idx];
        H_in[idx] = runIn;                      // packed exclusive prefix
        runIn += hv;
        runOut += H_out[idx];
    }
    #pragma unroll
    for (int k = 0; k < 4; k++) {
        int n = (r << 14) | (w << 2) | k;
        if (n < NN) {
            int di = (runIn >> (k * 8)) & 0xff;
            int dd = (runOut >> (k * 8)) & 0xff;
            deg_in[n] = di;
            norm_in[n]  = rsqrtf((float)max(di, 1));
            norm_out[n] = rsqrtf((float)max(dd, 1));
        }
    }
}

// ---------------- prefix scan trio over deg_in ----------------
__global__ void scan1(const int* __restrict__ deg_in,
                      int* __restrict__ excl, int* __restrict__ bsums, int n) {
    __shared__ int ws[16];
    int t = threadIdx.x;
    int i = blockIdx.x * 1024 + t;
    int v = (i < n) ? deg_in[i] : 0;
    int x = v;
    #pragma unroll
    for (int o = 1; o < 64; o <<= 1) {
        int y = __shfl_up(x, o, 64);
        if ((t & 63) >= o) x += y;
    }
    if ((t & 63) == 63) ws[t >> 6] = x;
    __syncthreads();
    if (t < 16) {
        int s = ws[t];
        #pragma unroll
        for (int o = 1; o < 16; o <<= 1) {
            int y = __shfl_up(s, o, 16);
            if (t >= o) s += y;
        }
        ws[t] = s;
    }
    __syncthreads();
    int wid = t >> 6;
    int pre = wid ? ws[wid - 1] : 0;
    if (i < n) excl[i] = pre + x - v;
    if (t == 1023) bsums[blockIdx.x] = ws[15];
}

__global__ void scan2(const int* __restrict__ bsums, int* __restrict__ boff, int nb,
                      int* __restrict__ total_out) {
    int t = threadIdx.x;
    int v = (t < nb) ? bsums[t] : 0;
    int x = v;
    #pragma unroll
    for (int o = 1; o < 64; o <<= 1) {
        int y = __shfl_up(x, o, 64);
        if (t >= o) x += y;
    }
    if (t < nb) boff[t] = x - v;
    if (t == 63) total_out[0] = x;
}

__global__ void scan3(int* __restrict__ off, const int* __restrict__ boff, int n) {
    int i = blockIdx.x * 1024 + threadIdx.x;
    if (i < n) off[i] += boff[blockIdx.x];
}

// ---------------- CSR fill: atomic-free (u8 local rank + slice-major 8-bit P) ----------------
__global__ void fill_kernel(const int* __restrict__ src, const int* __restrict__ dst,
                            const int* __restrict__ off, const unsigned char* __restrict__ rank_local,
                            const int* __restrict__ P, int* __restrict__ eidx, int E) {
    int e = blockIdx.x * blockDim.x + threadIdx.x;
    if (e < E) {
        int dd = dst[e];
        int s = e / EPS;
        size_t idx = ((size_t)(s * NRG + (dd >> 14)) << 12) + ((dd & 16383) >> 2);
        int pv = (P[idx] >> ((dd & 3) << 3)) & 0xff;
        eidx[off[dd] + (int)rank_local[e] + pv] = src[e];
    }
}

// ---- fused aggregate (depth-4 fp16 gather) + nin + bias + LN + LeakyReLU ----
template <bool PROJ, bool NOUTG>
__global__ __launch_bounds__(256) void agg_post(const __half* __restrict__ Yh, const int* __restrict__ off,
                                                const int* __restrict__ eidx, const float* __restrict__ nout,
                                                const float* __restrict__ nin,
                                                const float* __restrict__ bias, const float* __restrict__ gam,
                                                const float* __restrict__ bet, __half* __restrict__ Xo,
                                                const float* __restrict__ W3, float* __restrict__ Z, int n) {
    int w = threadIdx.x >> 6, lane = threadIdx.x & 63;
    int r = blockIdx.x * 4 + w;
    if (r >= n) return;
    int grp = lane >> 4;
    int f0 = (lane & 15) * 8;
    int s = off[r], e = off[r + 1];

    float af[8];
    #pragma unroll
    for (int i = 0; i < 8; i++) af[i] = 0.f;

    union U { float4 f; __half2 h[4]; };
    for (int j = s; j < e; j += 16) {
        int i0 = j + grp, i1 = i0 + 4, i2 = i0 + 8, i3 = i0 + 12;
        int s0 = (i0 < e) ? eidx[i0] : -1;
        int s1 = (i1 < e) ? eidx[i1] : -1;
        int s2 = (i2 < e) ? eidx[i2] : -1;
        int s3 = (i3 < e) ? eidx[i3] : -1;
        U u0, u1, u2, u3;
        float n0 = 1.f, n1 = 1.f, n2 = 1.f, n3 = 1.f;
        if (s0 >= 0) u0.f = *(const float4*)&Yh[(size_t)s0 * HID + f0];
        if (s1 >= 0) u1.f = *(const float4*)&Yh[(size_t)s1 * HID + f0];
        if (s2 >= 0) u2.f = *(const float4*)&Yh[(size_t)s2 * HID + f0];
        if (s3 >= 0) u3.f = *(const float4*)&Yh[(size_t)s3 * HID + f0];
        if (NOUTG) {
            if (s0 >= 0) n0 = nout[s0];
            if (s1 >= 0) n1 = nout[s1];
            if (s2 >= 0) n2 = nout[s2];
            if (s3 >= 0) n3 = nout[s3];
        }
        #define ACCUM(S_, U_, N_)                                           \
        if (S_ >= 0) {                                                      \
            _Pragma("unroll")                                               \
            for (int k = 0; k < 4; k++) {                                   \
                float2 f = __half22float2(U_.h[k]);                         \
                if (NOUTG) {                                                \
                    af[2 * k]     = fmaf(N_, f.x, af[2 * k]);               \
                    af[2 * k + 1] = fmaf(N_, f.y, af[2 * k + 1]);           \
                } else {                                                    \
                    af[2 * k] += f.x; af[2 * k + 1] += f.y;                 \
                }                                                           \
            }                                                               \
        }
        ACCUM(s0, u0, n0) ACCUM(s1, u1, n1) ACCUM(s2, u2, n2) ACCUM(s3, u3, n3)
        #undef ACCUM
    }
    #pragma unroll
    for (int i = 0; i < 8; i++) {
        af[i] += __shfl_xor(af[i], 16, 64);
        af[i] += __shfl_xor(af[i], 32, 64);
    }

    float ni = nin[r];
    float4 b0 = *(const float4*)&bias[f0];
    float4 b1 = *(const float4*)&bias[f0 + 4];
    float v[8];
    v[0] = af[0] * ni + b0.x; v[1] = af[1] * ni + b0.y;
    v[2] = af[2] * ni + b0.z; v[3] = af[3] * ni + b0.w;
    v[4] = af[4] * ni + b1.x; v[5] = af[5] * ni + b1.y;
    v[6] = af[6] * ni + b1.z; v[7] = af[7] * ni + b1.w;

    float sum = 0.f;
    #pragma unroll
    for (int i = 0; i < 8; i++) sum += v[i];
    #pragma unroll
    for (int o = 8; o >= 1; o >>= 1) sum += __shfl_xor(sum, o, 64);
    float mu = sum * (1.f / 128.f);

    float d[8], vs = 0.f;
    #pragma unroll
    for (int i = 0; i < 8; i++) { d[i] = v[i] - mu; vs += d[i] * d[i]; }
    #pragma unroll
    for (int o = 8; o >= 1; o >>= 1) vs += __shfl_xor(vs, o, 64);
    float rs = rsqrtf(vs * (1.f / 128.f) + 1e-5f);

    float4 g0 = *(const float4*)&gam[f0];
    float4 g1 = *(const float4*)&gam[f0 + 4];
    float4 e0 = *(const float4*)&bet[f0];
    float4 e1 = *(const float4*)&bet[f0 + 4];
    float x[8];
    x[0] = lrelu(d[0] * rs * g0.x + e0.x);
    x[1] = lrelu(d[1] * rs * g0.y + e0.y);
    x[2] = lrelu(d[2] * rs * g0.z + e0.z);
    x[3] = lrelu(d[3] * rs * g0.w + e0.w);
    x[4] = lrelu(d[4] * rs * g1.x + e1.x);
    x[5] = lrelu(d[5] * rs * g1.y + e1.y);
    x[6] = lrelu(d[6] * rs * g1.z + e1.z);
    x[7] = lrelu(d[7] * rs * g1.w + e1.w);

    if (PROJ) {
        float z0 = 0.f, z1 = 0.f;
        #pragma unroll
        for (int i = 0; i < 8; i++) {
            float2 w3 = *(const float2*)&W3[(f0 + i) * 2];
            z0 = fmaf(x[i], w3.x, z0);
            z1 = fmaf(x[i], w3.y, z1);
        }
        #pragma unroll
        for (int o = 8; o >= 1; o >>= 1) {
            z0 += __shfl_xor(z0, o, 64);
            z1 += __shfl_xor(z1, o, 64);
        }
        if (lane == 0) {
            float no = nout[r];
            *(float2*)&Z[r * 2] = make_float2(z0 * no, z1 * no);
        }
    } else {
        if (grp == 0) {
            union { __half2 h[4]; float4 f; } o;
            o.h[0] = __floats2half2_rn(x[0], x[1]);
            o.h[1] = __floats2half2_rn(x[2], x[3]);
            o.h[2] = __floats2half2_rn(x[4], x[5]);
            o.h[3] = __floats2half2_rn(x[6], x[7]);
            *(float4*)&Xo[(size_t)r * HID + f0] = o.f;
        }
    }
}

// ---------------- final aggregation (2 dims), 4-way unrolled ----------------
__global__ void agg3(const float* __restrict__ Z, const int* __restrict__ off,
                     const int* __restrict__ eidx, const float* __restrict__ nin,
                     const float* __restrict__ b3, float* __restrict__ out, int n) {
    int r = blockIdx.x * blockDim.x + threadIdx.x;
    if (r < n) {
        int s = off[r], e = off[r + 1];
        float p0 = 0.f, p1 = 0.f, q0 = 0.f, q1 = 0.f;
        float u0 = 0.f, u1 = 0.f, w0 = 0.f, w1 = 0.f;
        int j = s;
        for (; j + 3 < e; j += 4) {
            float2 v0 = *(const float2*)&Z[eidx[j] * 2];
            float2 v1 = *(const float2*)&Z[eidx[j + 1] * 2];
            float2 v2 = *(const float2*)&Z[eidx[j + 2] * 2];
            float2 v3 = *(const float2*)&Z[eidx[j + 3] * 2];
            p0 += v0.x; p1 += v0.y;
            q0 += v1.x; q1 += v1.y;
            u0 += v2.x; u1 += v2.y;
            w0 += v3.x; w1 += v3.y;
        }
        for (; j < e; ++j) {
            float2 v = *(const float2*)&Z[eidx[j] * 2];
            p0 += v.x; p1 += v.y;
        }
        float a0 = (p0 + q0) + (u0 + w0);
        float a1 = (p1 + q1) + (u1 + w1);
        float ni = nin[r];
        out[r * 2 + 0] = a0 * ni + b3[0];
        out[r * 2 + 1] = a1 * ni + b3[1];
    }
}

extern "C" void kernel_launch(void* const* d_in, const int* in_sizes, int n_in,
                              void* d_out, int out_size, void* d_ws, size_t ws_size,
                              hipStream_t stream) {
    const float* feat = (const float*)d_in[0];
    const int* src = (const int*)d_in[1];
    const int* dst = (const int*)d_in[2];
    const float* W1 = (const float*)d_in[3];
    const float* b1 = (const float*)d_in[4];
    const float* W2 = (const float*)d_in[5];
    const float* b2 = (const float*)d_in[6];
    const float* W3 = (const float*)d_in[7];
    const float* b3 = (const float*)d_in[8];
    const float* g1 = (const float*)d_in[9];
    const float* be1 = (const float*)d_in[10];
    const float* g2 = (const float*)d_in[11];
    const float* be2 = (const float*)d_in[12];
    float* out = (float*)d_out;

    char* p = (char*)d_ws;
    auto carve = [&](size_t bytes) -> char* {
        char* q = p;
        p += (bytes + 255) & ~(size_t)255;
        return q;
    };
    int* deg_in  = (int*)carve(NN * 4);
    float* norm_out = (float*)carve(NN * 4);
    float* norm_in  = (float*)carve(NN * 4);
    int* off     = (int*)carve((NN + 1) * 4);
    int* bsums   = (int*)carve(64 * 4);
    int* boff    = (int*)carve(64 * 4);
    int* eidx    = (int*)carve((size_t)NE * 4);
    unsigned char* rank_local = (unsigned char*)carve((size_t)NE);
    int* H_in  = (int*)carve((size_t)NSL * NRG * PLW * 4);   // 8 MB, slice-major; becomes P in-place
    int* H_out = (int*)carve((size_t)NSL * NRG * PLW * 4);   // 8 MB
    _Float16* W2sw = (_Float16*)carve(16384 * 2);
    _Float16* Yh = (_Float16*)carve((size_t)NN * HID * 2);
    __half* Xh = (__half*)carve((size_t)NN * HID * 2);
    float* Z = (float*)carve((size_t)NN * 2 * 4);

    // phase1: hist (512) || W2 convert (64) || GEMM-1 self-converting (782) — one launch
    phase1<<<HB + 64 + GEMMB, 256, 0, stream>>>(src, dst, rank_local, H_in, H_out,
                                                W1, W2, W2sw, feat, Yh, NN);

    // packed-byte exclusive prefix over slices (P in-place) + degrees + norms
    prefix_k<<<64, 256, 0, stream>>>(H_in, H_out, deg_in, norm_in, norm_out);

    // scan trio over deg_in -> off
    int nb = (NN + 1023) / 1024;  // 49
    scan1<<<nb, 1024, 0, stream>>>(deg_in, off, bsums, NN);
    scan2<<<1, 64, 0, stream>>>(bsums, boff, nb, off + NN);
    scan3<<<nb, 1024, 0, stream>>>(off, boff, NN);

    // CSR fill (atomic-free, slice-major P window per block)
    fill_kernel<<<(NE + 255) / 256, 256, 0, stream>>>(src, dst, off, rank_local, H_in, eidx, NE);

    // layer 1 aggregation (folds nout[src]) -> fp16 X
    agg_post<false, true><<<(NN + 3) / 4, 256, 0, stream>>>((const __half*)Yh, off, eidx, norm_out, norm_in,
                                                            b1, g1, be1, Xh, nullptr, nullptr, NN);
    // layer 2 GEMM (fp16 MFMA, output pre-scaled by norm_out)
    gemm2<<<GEMMB, 256, 0, stream>>>((const _Float16*)Xh, W2sw, norm_out, Yh, NN);
    // layer 2 aggregation (Yh pre-scaled) fused with layer-3 projection -> Z
    agg_post<true, false><<<(NN + 3) / 4, 256, 0, stream>>>((const __half*)Yh, off, eidx, norm_out, norm_in,
                                                            b2, g2, be2, nullptr, W3, Z, NN);
    // layer 3 aggregation -> out
    agg3<<<(NN + 255) / 256, 256, 0, stream>>>(Z, off, eidx, norm_in, b3, out, NN);
}